// Round 10
// baseline (3996.396 us; speedup 1.0000x reference)
//
#include <hip/hip_runtime.h>
#include <math.h>

typedef __attribute__((ext_vector_type(8))) short short8v;    // 8 bf16
typedef __attribute__((ext_vector_type(4))) float f32x4;
typedef __attribute__((ext_vector_type(16))) float f32x16;
typedef unsigned long long u64;
typedef unsigned short ushort_t;

constexpr int Bb = 4;
constexpr int Ll = 512;
constexpr int Dk = 2048;
constexpr int Vv = 32000;
constexpr int Tt = 1024;
constexpr int Mrows = Bb * Ll;  // 2048

// main GEMM geometry: 256x256 tile, BK=32, 8 waves (2 row x 4 col),
// 32x32x16 MFMA: per wave 128x64 out = 4x2 f32x16 acc.
constexpr int BM = 256;
constexpr int BN = 256;
constexpr int BK = 32;
constexpr int NKT = Dk / BK;     // 64 K-tiles
constexpr int NBX = Mrows / BM;  // 8
constexpr int NBY = Vv / BN;     // 125
constexpr int NWG = NBX * NBY;   // 1000 (divisible by 8)
constexpr int CHUNK = NWG / 8;   // 125

constexpr int KCAND = 8;          // rescored candidates per row
constexpr int CAND_STRIDE = 500;  // u64 per row; main path uses first 250

// fallback geometry (small-ws path, 128x128 reg-staged, verified 16x16 path)
constexpr int FBM = 128;
constexpr int FBN = 128;
constexpr int FNVB = Vv / FBN;  // 250

// ---- workspace layout (bytes) ----
// winv : f32[32000]        @ 0          (131072 B slot)
// best : u64[2048]         @ 131072     (16384 B)
// sel  : i32[2048*8]       @ 147456     (65536 B)
// cand : u64[2048*500]     @ 262144     (8192000 B)
// Abf  : bf16[2048*2048]   @ 8454144    (8388608 B)
// Wbf  : bf16[32000*2048]  @ 16842752   (131072000 B)  -> total 147914752 B
constexpr size_t WS_NEEDED = 147914752ull;

__device__ __forceinline__ unsigned int fkey(float f) {
    unsigned int u = __float_as_uint(f);
    return (u & 0x80000000u) ? ~u : (u | 0x80000000u);
}
__device__ __forceinline__ void top2(u64& b1, u64& b2, u64 p) {
    if (p > b1) { b2 = b1; b1 = p; }
    else if (p > b2) { b2 = p; }
}
__device__ __forceinline__ u64 shfl64(u64 x, int m) {
    unsigned lo = __shfl_xor((unsigned)x, m, 64);
    unsigned hi = __shfl_xor((unsigned)(x >> 32), m, 64);
    return ((u64)hi << 32) | lo;
}
__device__ __forceinline__ ushort_t bftrunc(float x) {
    return (ushort_t)(__float_as_uint(x) >> 16);
}
// async global->LDS, 16B per lane; lds dst wave-uniform base (HW adds lane*16)
__device__ __forceinline__ void gload_lds16(const void* g, void* l) {
    __builtin_amdgcn_global_load_lds(
        (const __attribute__((address_space(1))) unsigned int*)g,
        (__attribute__((address_space(3))) unsigned int*)l, 16, 0, 0);
}

// ---------------- convert A: f32 -> bf16 row-major ----------------
__global__ __launch_bounds__(256) void convertA_kernel(const float* __restrict__ A,
                                                       ushort_t* __restrict__ Ab) {
    int i = blockIdx.x * blockDim.x + threadIdx.x;  // 8 elems per thread
    const float4* src = (const float4*)A;
    float4 x = src[i * 2], y = src[i * 2 + 1];
    ushort_t o[8] = {bftrunc(x.x), bftrunc(x.y), bftrunc(x.z), bftrunc(x.w),
                     bftrunc(y.x), bftrunc(y.y), bftrunc(y.z), bftrunc(y.w)};
    *(int4*)(Ab + (size_t)i * 8) = *(const int4*)o;
}

// ------------- convert W: f32 -> bf16 row-major, fused winv -------------
__global__ __launch_bounds__(256) void convertW_kernel(const float* __restrict__ W,
                                                       ushort_t* __restrict__ Wb,
                                                       float* __restrict__ winv) {
    int wave = (blockIdx.x * blockDim.x + threadIdx.x) >> 6;
    int lane = threadIdx.x & 63;
    if (wave >= Vv) return;
    const float4* row = (const float4*)(W + (size_t)wave * Dk);
    ushort4* orow = (ushort4*)(Wb + (size_t)wave * Dk);
    float s = 0.f;
#pragma unroll
    for (int i = 0; i < Dk / 4 / 64; ++i) {
        float4 v = row[lane + 64 * i];
        s = fmaf(v.x, v.x, s); s = fmaf(v.y, v.y, s);
        s = fmaf(v.z, v.z, s); s = fmaf(v.w, v.w, s);
        ushort4 o;
        o.x = bftrunc(v.x); o.y = bftrunc(v.y);
        o.z = bftrunc(v.z); o.w = bftrunc(v.w);
        orow[lane + 64 * i] = o;
    }
#pragma unroll
    for (int off = 32; off; off >>= 1) s += __shfl_down(s, off, 64);
    if (lane == 0) winv[wave] = 1.0f / sqrtf(s);
}

// ---------------- wnorm only (fallback path) ----------------
__global__ __launch_bounds__(256) void wnorm_kernel(const float* __restrict__ W,
                                                    float* __restrict__ winv) {
    int wave = (blockIdx.x * blockDim.x + threadIdx.x) >> 6;
    int lane = threadIdx.x & 63;
    if (wave >= Vv) return;
    const float4* row = (const float4*)(W + (size_t)wave * Dk);
    float s = 0.f;
#pragma unroll
    for (int i = 0; i < Dk / 4 / 64; ++i) {
        float4 v = row[lane + 64 * i];
        s = fmaf(v.x, v.x, s); s = fmaf(v.y, v.y, s);
        s = fmaf(v.z, v.z, s); s = fmaf(v.w, v.w, s);
    }
#pragma unroll
    for (int off = 32; off; off >>= 1) s += __shfl_down(s, off, 64);
    if (lane == 0) winv[wave] = 1.0f / sqrtf(s);
}

__global__ void init_best_kernel(u64* __restrict__ best) {
    int i = blockIdx.x * blockDim.x + threadIdx.x;
    if (i < Mrows) best[i] = 0ull;
}

// ========== Kernel 3 (main): 32x32x16-MFMA bf16 GEMM + per-block top-2 ==========
// LDS: 16 subtiles per operand per buffer; subtile s = rowgrp g (32 rows) x
// kchunk c (16 k), s = g*2+c, at ushort offset s*512. Lane l owns 8 bf16 at
// l*16B -> (row = g*32 + (l&31), k = c*16 + (l>>5)*8 .. +7).
// Fragment convention mirrors the verified 16x16 path: m/n = l&31,
// k = (l>>5)*8+j. C/D layout (HW-verified m74/m101): col = l&31,
// row = (reg&3) + 8*(reg>>2) + 4*(l>>5).
__global__ __launch_bounds__(512, 2) void score_topk_kernel(
    const ushort_t* __restrict__ Ab, const ushort_t* __restrict__ Wb,
    const float* __restrict__ winv, u64* __restrict__ cand) {
    __shared__ __align__(16) ushort_t Alds[2][8192];  // 2 x 16 KB
    __shared__ __align__(16) ushort_t Wlds[2][8192];  // 2 x 16 KB

    // XCD-aware bijective swizzle: 1000 = 8 x 125
    const int orig = blockIdx.x;
    const int swz = (orig & 7) * CHUNK + (orig >> 3);
    const int bx = swz & (NBX - 1);
    const int by = swz >> 3;
    const int row0 = bx * BM;
    const int v0 = by * BN;

    const int tid = threadIdx.x;
    const int lane = tid & 63;
    const int w = tid >> 6;   // 0..7
    const int wr = w >> 2;    // 0..1 -> rows wr*128..+127
    const int wc = w & 3;     // 0..3 -> cols wc*64..+63
    const int l31 = lane & 31;
    const int l5 = lane >> 5;

    // stage sources: wave w stages rowgrp w of A (subs 2w,2w+1) and colgrp w of W
    const ushort_t* sA = Ab + (size_t)(row0 + w * 32 + l31) * Dk + l5 * 8;
    const ushort_t* sW = Wb + (size_t)(v0 + w * 32 + l31) * Dk + l5 * 8;

    f32x16 acc[4][2];
#pragma unroll
    for (int i = 0; i < 4; ++i)
#pragma unroll
        for (int j = 0; j < 2; ++j)
#pragma unroll
            for (int r = 0; r < 16; ++r) acc[i][j][r] = 0.f;

    auto stage = [&](int buf, int t) {
        const int k0 = t * BK;
        gload_lds16(sA + k0, &Alds[buf][(2 * w) * 512]);       // kchunk 0
        gload_lds16(sA + k0 + 16, &Alds[buf][(2 * w + 1) * 512]);  // kchunk 1
        gload_lds16(sW + k0, &Wlds[buf][(2 * w) * 512]);
        gload_lds16(sW + k0 + 16, &Wlds[buf][(2 * w + 1) * 512]);
    };

    stage(0, 0);
    __syncthreads();  // tile 0 resident

    int cur = 0;
    for (int t = 0; t < NKT; ++t) {
        if (t + 1 < NKT) stage(cur ^ 1, t + 1);  // issue next tile's loads first
        const short8v* Ap = (const short8v*)&Alds[cur][0];
        const short8v* Wp = (const short8v*)&Wlds[cur][0];
        __builtin_amdgcn_s_setprio(1);
#pragma unroll
        for (int c = 0; c < 2; ++c) {
            short8v a[4], b[2];
#pragma unroll
            for (int mf = 0; mf < 4; ++mf)
                a[mf] = Ap[((wr * 4 + mf) * 2 + c) * 64 + lane];
#pragma unroll
            for (int nf = 0; nf < 2; ++nf)
                b[nf] = Wp[((wc * 2 + nf) * 2 + c) * 64 + lane];
#pragma unroll
            for (int mf = 0; mf < 4; ++mf)
#pragma unroll
                for (int nf = 0; nf < 2; ++nf)
                    acc[mf][nf] = __builtin_amdgcn_mfma_f32_32x32x16_bf16(
                        a[mf], b[nf], acc[mf][nf], 0, 0, 0);
        }
        __builtin_amdgcn_s_setprio(0);
        __syncthreads();  // my reads done; next tile's stage drained
        cur ^= 1;
    }

    // ---- epilogue: scale by winv, per-row top-2 within this 256-col block ----
    float wv[2];
#pragma unroll
    for (int nf = 0; nf < 2; ++nf) wv[nf] = winv[v0 + wc * 64 + nf * 32 + l31];

    u64(*red)[8] = (u64(*)[8]) & Alds[0][0];  // 256 rows x 8 u64 = 16 KB alias
#pragma unroll
    for (int mf = 0; mf < 4; ++mf) {
#pragma unroll
        for (int reg = 0; reg < 16; ++reg) {
            u64 b1 = 0, b2 = 0;
#pragma unroll
            for (int nf = 0; nf < 2; ++nf) {
                float s = acc[mf][nf][reg] * wv[nf];
                int v = v0 + wc * 64 + nf * 32 + l31;
                u64 p = ((u64)fkey(s) << 32) | (unsigned)(Vv - 1 - v);
                top2(b1, b2, p);
            }
            // reduce over the 32 cols: xor masks <32 stay within the half
#pragma unroll
            for (int m = 1; m < 32; m <<= 1) {
                u64 o1 = shfl64(b1, m);
                u64 o2 = shfl64(b2, m);
                top2(b1, b2, o1);
                top2(b1, b2, o2);
            }
            if (l31 == 0) {
                int rl = wr * 128 + mf * 32 + (reg & 3) + 8 * (reg >> 2) + 4 * l5;
                red[rl][wc * 2] = b1;
                red[rl][wc * 2 + 1] = b2;
            }
        }
    }
    __syncthreads();
    if (tid < BM) {
        u64 b1 = red[tid][0], b2 = red[tid][1];
#pragma unroll
        for (int j = 2; j < 8; ++j) top2(b1, b2, red[tid][j]);
        u64* c = cand + (size_t)(row0 + tid) * CAND_STRIDE + by * 2;
        c[0] = b1;
        c[1] = b2;
    }
}

// ------ fallback epilogue (128x128 path, verified 16x16) ------
template <typename LdsT>
__device__ __forceinline__ void topk_epilogue_f(f32x4 (&acc)[4][4], LdsT* ldsbase,
                                                const float* __restrict__ winv,
                                                u64* __restrict__ cand, int row0, int v0,
                                                int vby, int tid, int lane, int wr,
                                                int wc) {
    const int cbase = v0 + wc * 64 + (lane & 15);
    float wv[4];
#pragma unroll
    for (int nf = 0; nf < 4; ++nf) wv[nf] = winv[cbase + nf * 16];

    u64(*red)[4] = (u64(*)[4])ldsbase;
#pragma unroll
    for (int mf = 0; mf < 4; ++mf) {
#pragma unroll
        for (int reg = 0; reg < 4; ++reg) {
            u64 b1 = 0, b2 = 0;
#pragma unroll
            for (int nf = 0; nf < 4; ++nf) {
                float s = acc[mf][nf][reg] * wv[nf];
                int v = cbase + nf * 16;
                u64 p = ((u64)fkey(s) << 32) | (unsigned)(Vv - 1 - v);
                top2(b1, b2, p);
            }
#pragma unroll
            for (int m = 1; m < 16; m <<= 1) {
                u64 o1 = shfl64(b1, m);
                u64 o2 = shfl64(b2, m);
                top2(b1, b2, o1);
                top2(b1, b2, o2);
            }
            if ((lane & 15) == 0) {
                int rl = wr * 64 + mf * 16 + ((lane >> 4) << 2) + reg;
                red[rl][wc * 2] = b1;
                red[rl][wc * 2 + 1] = b2;
            }
        }
    }
    __syncthreads();
    if (tid < FBM) {
        u64 b1 = red[tid][0], b2 = red[tid][1];
        top2(b1, b2, red[tid][2]);
        top2(b1, b2, red[tid][3]);
        u64* c = cand + (size_t)(row0 + tid) * CAND_STRIDE + vby * 2;
        c[0] = b1;
        c[1] = b2;
    }
}

// ---------- Kernel 3 (fallback, small ws): reg-staged f32->bf16 GEMM ----------
__global__ __launch_bounds__(256) void score_topk_fallback(
    const float* __restrict__ A, const float* __restrict__ W,
    const float* __restrict__ winv, u64* __restrict__ cand) {
    __shared__ __align__(16) short Albuf[4096];
    __shared__ __align__(16) short Wlbuf[4096];

    const int tid = threadIdx.x;
    const int row0 = blockIdx.x * FBM;
    const int v0 = blockIdx.y * FBN;
    const int lane = tid & 63;
    const int wid = tid >> 6;
    const int wr = wid >> 1, wc = wid & 1;

    const int rA = ((tid >> 6) << 4) + (tid & 15);
    const int kk = ((tid >> 4) & 3) * 8;

    const float* pa = A + (size_t)(row0 + rA) * Dk + kk;
    const float* pw = W + (size_t)(v0 + rA) * Dk + kk;

    float4 fa0, fa1, fa2, fa3, fw0, fw1, fw2, fw3;
    auto ld4 = [](const float* p) { return *(const float4*)p; };
    auto load_regs = [&](int k0) {
        fa0 = ld4(pa + k0); fa1 = ld4(pa + k0 + 4);
        fa2 = ld4(pa + k0 + (size_t)64 * Dk); fa3 = ld4(pa + k0 + (size_t)64 * Dk + 4);
        fw0 = ld4(pw + k0); fw1 = ld4(pw + k0 + 4);
        fw2 = ld4(pw + k0 + (size_t)64 * Dk); fw3 = ld4(pw + k0 + (size_t)64 * Dk + 4);
    };
    auto pk = [](float lo, float hi) {
        return (int)((__float_as_uint(lo) >> 16) | (__float_as_uint(hi) & 0xFFFF0000u));
    };
    auto cv = [&](float4 a, float4 b) {
        int4 r; r.x = pk(a.x, a.y); r.y = pk(a.z, a.w);
        r.z = pk(b.x, b.y); r.w = pk(b.z, b.w); return r;
    };
    auto write_lds = [&]() {
        *(int4*)(Albuf + tid * 8) = cv(fa0, fa1);
        *(int4*)(Albuf + tid * 8 + 2048) = cv(fa2, fa3);
        *(int4*)(Wlbuf + tid * 8) = cv(fw0, fw1);
        *(int4*)(Wlbuf + tid * 8 + 2048) = cv(fw2, fw3);
    };

    f32x4 acc[4][4];
#pragma unroll
    for (int i = 0; i < 4; ++i)
#pragma unroll
        for (int j = 0; j < 4; ++j) acc[i][j] = (f32x4){0.f, 0.f, 0.f, 0.f};

    load_regs(0);
    for (int kt = 0; kt < Dk / 32; ++kt) {
        write_lds();
        __syncthreads();
        if (kt + 1 < Dk / 32) load_regs((kt + 1) * 32);
        short8v af[4], bf[4];
        const short8v* Ap = (const short8v*)Albuf;
        const short8v* Wp = (const short8v*)Wlbuf;
#pragma unroll
        for (int mf = 0; mf < 4; ++mf) af[mf] = Ap[(wr * 4 + mf) * 64 + lane];
#pragma unroll
        for (int nf = 0; nf < 4; ++nf) bf[nf] = Wp[(wc * 4 + nf) * 64 + lane];
#pragma unroll
        for (int mf = 0; mf < 4; ++mf)
#pragma unroll
            for (int nf = 0; nf < 4; ++nf)
                acc[mf][nf] = __builtin_amdgcn_mfma_f32_16x16x32_bf16(
                    af[mf], bf[nf], acc[mf][nf], 0, 0, 0);
        __syncthreads();
    }

    topk_epilogue_f(acc, Albuf, winv, cand, row0, v0, blockIdx.y, tid, lane, wr, wc);
}

// ---------------- Kernel 4: per-row top-8 of nents candidates ----------------
__global__ __launch_bounds__(256) void topk_kernel(const u64* __restrict__ cand,
                                                   int* __restrict__ sel, int nents) {
    int row = blockIdx.x * 4 + (threadIdx.x >> 6);
    int lane = threadIdx.x & 63;
    if (row >= Mrows) return;
    const u64* c = cand + (size_t)row * CAND_STRIDE;
    u64 v[8];
#pragma unroll
    for (int i = 0; i < 8; ++i) {
        int idx = lane + i * 64;
        v[i] = (idx < nents) ? c[idx] : 0ull;
    }
#pragma unroll
    for (int it = 0; it < KCAND; ++it) {
        u64 lm = 0;
#pragma unroll
        for (int i = 0; i < 8; ++i) lm = v[i] > lm ? v[i] : lm;
#pragma unroll
        for (int m = 32; m; m >>= 1) {
            u64 o = shfl64(lm, m);
            lm = o > lm ? o : lm;
        }
#pragma unroll
        for (int i = 0; i < 8; ++i)
            if (v[i] == lm) v[i] = 0;  // packed values unique -> removes one
        if (lane == 0) sel[row * KCAND + it] = Vv - 1 - (int)(unsigned)(lm & 0xFFFFFFFFu);
    }
}

// ---------------- Kernel 5: exact f32 rescore of top-8 ----------------
__global__ __launch_bounds__(256) void rescore_kernel(
    const float* __restrict__ A, const float* __restrict__ W,
    const float* __restrict__ winv, const int* __restrict__ sel,
    u64* __restrict__ best) {
    int gw = (int)((blockIdx.x * blockDim.x + threadIdx.x) >> 6);
    int lane = threadIdx.x & 63;
    if (gw >= Mrows * KCAND) return;
    int row = gw >> 3, c = gw & 7;
    int v = sel[row * KCAND + c];
    const float4* a = (const float4*)(A + (size_t)row * Dk);
    const float4* w = (const float4*)(W + (size_t)v * Dk);
    float s = 0.f;
#pragma unroll
    for (int i = 0; i < Dk / 4 / 64; ++i) {
        float4 x = a[lane + 64 * i], y = w[lane + 64 * i];
        s = fmaf(x.x, y.x, s); s = fmaf(x.y, y.y, s);
        s = fmaf(x.z, y.z, s); s = fmaf(x.w, y.w, s);
    }
#pragma unroll
    for (int m = 32; m; m >>= 1) s += __shfl_xor(s, m, 64);
    if (lane == 0) {
        u64 p = ((u64)fkey(s * winv[v]) << 32) | (unsigned)(Vv - 1 - v);
        atomicMax(best + row, p);
    }
}

// ---------------- Kernel 6: blend + emit quantize_index ----------------
__global__ __launch_bounds__(256) void blend_kernel(
    const float* __restrict__ emb, const int* __restrict__ ids,
    const u64* __restrict__ best, float* __restrict__ out) {
    int row = blockIdx.x;
    int b = row / Tt;
    int t = row % Tt;
    int idx;
    if (t < Ll) {
        idx = Vv - 1 - (int)(best[b * Ll + t] & 0xFFFFFFFFu);
    } else {
        idx = ids[row];
    }
    const float4* src = (const float4*)(emb + (size_t)idx * Dk);
    float4* dst = (float4*)(out + (size_t)row * Dk);
    for (int i = threadIdx.x; i < Dk / 4; i += blockDim.x) dst[i] = src[i];
    if (t < Ll && threadIdx.x == 0) {
        out[(size_t)Bb * Tt * Dk + (size_t)(b * Ll + t)] = (float)idx;
    }
}

extern "C" void kernel_launch(void* const* d_in, const int* in_sizes, int n_in,
                              void* d_out, int out_size, void* d_ws, size_t ws_size,
                              hipStream_t stream) {
    const float* encoder_outs = (const float*)d_in[0];
    const float* embed_weight = (const float*)d_in[1];
    const int* input_ids = (const int*)d_in[2];

    float* out = (float*)d_out;

    float* winv = (float*)d_ws;
    u64* best = (u64*)((char*)d_ws + 131072);
    int* sel = (int*)((char*)d_ws + 147456);
    u64* cand = (u64*)((char*)d_ws + 262144);
    ushort_t* Abf = (ushort_t*)((char*)d_ws + 8454144);
    ushort_t* Wbf = (ushort_t*)((char*)d_ws + 16842752);

    init_best_kernel<<<(Mrows + 255) / 256, 256, 0, stream>>>(best);

    if (ws_size >= WS_NEEDED) {
        convertA_kernel<<<Mrows * Dk / 8 / 256, 256, 0, stream>>>(encoder_outs, Abf);
        convertW_kernel<<<Vv * 64 / 256, 256, 0, stream>>>(embed_weight, Wbf, winv);
        score_topk_kernel<<<NWG, 512, 0, stream>>>(Abf, Wbf, winv, cand);
        topk_kernel<<<Mrows / 4, 256, 0, stream>>>(cand, sel, 2 * NBY);  // 250
    } else {
        wnorm_kernel<<<Vv * 64 / 256, 256, 0, stream>>>(embed_weight, winv);
        dim3 grid(Mrows / FBM, Vv / FBN);
        score_topk_fallback<<<grid, 256, 0, stream>>>(encoder_outs, embed_weight, winv,
                                                      cand);
        topk_kernel<<<Mrows / 4, 256, 0, stream>>>(cand, sel, 2 * FNVB);  // 500
    }
    rescore_kernel<<<Mrows * KCAND / 4, 256, 0, stream>>>(encoder_outs, embed_weight,
                                                          winv, sel, best);
    blend_kernel<<<Bb * Tt, 256, 0, stream>>>(embed_weight, input_ids, best, out);
}

// Round 11
// 1594.726 us; speedup vs baseline: 2.5060x; 2.5060x over previous
//
#include <hip/hip_runtime.h>
#include <math.h>

typedef __attribute__((ext_vector_type(8))) short short8v;    // 8 bf16
typedef __attribute__((ext_vector_type(4))) float f32x4;
typedef __attribute__((ext_vector_type(16))) float f32x16;
typedef unsigned long long u64;
typedef unsigned short ushort_t;

constexpr int Bb = 4;
constexpr int Ll = 512;
constexpr int Dk = 2048;
constexpr int Vv = 32000;
constexpr int Tt = 1024;
constexpr int Mrows = Bb * Ll;  // 2048

// main GEMM geometry: 256x256 tile, BK=32, 16 waves (4x4 grid, 64x64 out each),
// 32x32x16 MFMA: acc[2][2] f32x16 = 64 VGPRs (4 aligned tuples -> no spill).
constexpr int BM = 256;
constexpr int BN = 256;
constexpr int BK = 32;
constexpr int NKT = Dk / BK;     // 64 K-tiles
constexpr int NBX = Mrows / BM;  // 8
constexpr int NBY = Vv / BN;     // 125
constexpr int NWG = NBX * NBY;   // 1000 (divisible by 8)
constexpr int CHUNK = NWG / 8;   // 125

constexpr int KCAND = 8;          // rescored candidates per row
constexpr int CAND_STRIDE = 500;  // u64 per row; main path uses first 250

// fallback geometry (small-ws path, 128x128 reg-staged, verified 16x16 path)
constexpr int FBM = 128;
constexpr int FBN = 128;
constexpr int FNVB = Vv / FBN;  // 250

// ---- workspace layout (bytes) ----
// winv : f32[32000]        @ 0          (131072 B slot)
// best : u64[2048]         @ 131072     (16384 B)
// sel  : i32[2048*8]       @ 147456     (65536 B)
// cand : u64[2048*500]     @ 262144     (8192000 B)
// Abf  : bf16[2048*2048]   @ 8454144    (8388608 B)
// Wbf  : bf16[32000*2048]  @ 16842752   (131072000 B)  -> total 147914752 B
constexpr size_t WS_NEEDED = 147914752ull;

__device__ __forceinline__ unsigned int fkey(float f) {
    unsigned int u = __float_as_uint(f);
    return (u & 0x80000000u) ? ~u : (u | 0x80000000u);
}
__device__ __forceinline__ void top2(u64& b1, u64& b2, u64 p) {
    if (p > b1) { b2 = b1; b1 = p; }
    else if (p > b2) { b2 = p; }
}
__device__ __forceinline__ u64 shfl64(u64 x, int m) {
    unsigned lo = __shfl_xor((unsigned)x, m, 64);
    unsigned hi = __shfl_xor((unsigned)(x >> 32), m, 64);
    return ((u64)hi << 32) | lo;
}
__device__ __forceinline__ ushort_t bftrunc(float x) {
    return (ushort_t)(__float_as_uint(x) >> 16);
}
// async global->LDS, 16B per lane; lds dst wave-uniform base (HW adds lane*16)
__device__ __forceinline__ void gload_lds16(const void* g, void* l) {
    __builtin_amdgcn_global_load_lds(
        (const __attribute__((address_space(1))) unsigned int*)g,
        (__attribute__((address_space(3))) unsigned int*)l, 16, 0, 0);
}

// ---------------- convert A: f32 -> bf16 row-major ----------------
__global__ __launch_bounds__(256) void convertA_kernel(const float* __restrict__ A,
                                                       ushort_t* __restrict__ Ab) {
    int i = blockIdx.x * blockDim.x + threadIdx.x;  // 8 elems per thread
    const float4* src = (const float4*)A;
    float4 x = src[i * 2], y = src[i * 2 + 1];
    ushort_t o[8] = {bftrunc(x.x), bftrunc(x.y), bftrunc(x.z), bftrunc(x.w),
                     bftrunc(y.x), bftrunc(y.y), bftrunc(y.z), bftrunc(y.w)};
    *(int4*)(Ab + (size_t)i * 8) = *(const int4*)o;
}

// ------------- convert W: f32 -> bf16 row-major, fused winv -------------
__global__ __launch_bounds__(256) void convertW_kernel(const float* __restrict__ W,
                                                       ushort_t* __restrict__ Wb,
                                                       float* __restrict__ winv) {
    int wave = (blockIdx.x * blockDim.x + threadIdx.x) >> 6;
    int lane = threadIdx.x & 63;
    if (wave >= Vv) return;
    const float4* row = (const float4*)(W + (size_t)wave * Dk);
    ushort4* orow = (ushort4*)(Wb + (size_t)wave * Dk);
    float s = 0.f;
#pragma unroll
    for (int i = 0; i < Dk / 4 / 64; ++i) {
        float4 v = row[lane + 64 * i];
        s = fmaf(v.x, v.x, s); s = fmaf(v.y, v.y, s);
        s = fmaf(v.z, v.z, s); s = fmaf(v.w, v.w, s);
        ushort4 o;
        o.x = bftrunc(v.x); o.y = bftrunc(v.y);
        o.z = bftrunc(v.z); o.w = bftrunc(v.w);
        orow[lane + 64 * i] = o;
    }
#pragma unroll
    for (int off = 32; off; off >>= 1) s += __shfl_down(s, off, 64);
    if (lane == 0) winv[wave] = 1.0f / sqrtf(s);
}

// ---------------- wnorm only (fallback path) ----------------
__global__ __launch_bounds__(256) void wnorm_kernel(const float* __restrict__ W,
                                                    float* __restrict__ winv) {
    int wave = (blockIdx.x * blockDim.x + threadIdx.x) >> 6;
    int lane = threadIdx.x & 63;
    if (wave >= Vv) return;
    const float4* row = (const float4*)(W + (size_t)wave * Dk);
    float s = 0.f;
#pragma unroll
    for (int i = 0; i < Dk / 4 / 64; ++i) {
        float4 v = row[lane + 64 * i];
        s = fmaf(v.x, v.x, s); s = fmaf(v.y, v.y, s);
        s = fmaf(v.z, v.z, s); s = fmaf(v.w, v.w, s);
    }
#pragma unroll
    for (int off = 32; off; off >>= 1) s += __shfl_down(s, off, 64);
    if (lane == 0) winv[wave] = 1.0f / sqrtf(s);
}

__global__ void init_best_kernel(u64* __restrict__ best) {
    int i = blockIdx.x * blockDim.x + threadIdx.x;
    if (i < Mrows) best[i] = 0ull;
}

// ========== Kernel 3 (main): 16-wave 32x32x16-MFMA bf16 GEMM + top-2 ==========
// LDS per operand per buffer: 16 subtiles s = g*2+c (g = 32-row group 0..7,
// c = 16-k chunk 0..1) at ushort offset s*512; lane l owns 8 bf16 at l*16B ->
// (row = g*32 + (l&31), k = c*16 + (l>>5)*8 .. +7). gload_lds-linear.
// Wave w stages subtile w of A and of W (2 gloads/wave/tile, same as R9).
// Wave grid 4x4: wave (wrr,wcc) computes rows wrr*64..+63 x cols wcc*64..+63
// via 2x2 32x32 fragments; 8 MFMA/wave/tile (R9: 16) at identical FLOPs.
// C/D layout (HW-verified m74/m101): col = l&31, row = (reg&3)+8*(reg>>2)+4*(l>>5).
__global__ __launch_bounds__(1024, 4) void score_topk_kernel(
    const ushort_t* __restrict__ Ab, const ushort_t* __restrict__ Wb,
    const float* __restrict__ winv, u64* __restrict__ cand) {
    __shared__ __align__(16) ushort_t Alds[2][8192];  // 2 x 16 KB
    __shared__ __align__(16) ushort_t Wlds[2][8192];  // 2 x 16 KB

    // XCD-aware bijective swizzle: 1000 = 8 x 125
    const int orig = blockIdx.x;
    const int swz = (orig & 7) * CHUNK + (orig >> 3);
    const int bx = swz & (NBX - 1);
    const int by = swz >> 3;
    const int row0 = bx * BM;
    const int v0 = by * BN;

    const int tid = threadIdx.x;
    const int lane = tid & 63;
    const int w = tid >> 6;    // 0..15
    const int wrr = w >> 2;    // 0..3 -> rows wrr*64..+63
    const int wcc = w & 3;     // 0..3 -> cols wcc*64..+63
    const int l31 = lane & 31;
    const int l5 = lane >> 5;

    // stage sources: wave w stages subtile w (g = w>>1, c = w&1) of A and W
    const int sg = w >> 1, sc = w & 1;
    const ushort_t* sA = Ab + (size_t)(row0 + sg * 32 + l31) * Dk + sc * 16 + l5 * 8;
    const ushort_t* sW = Wb + (size_t)(v0 + sg * 32 + l31) * Dk + sc * 16 + l5 * 8;

    f32x16 acc[2][2];
#pragma unroll
    for (int i = 0; i < 2; ++i)
#pragma unroll
        for (int j = 0; j < 2; ++j)
#pragma unroll
            for (int r = 0; r < 16; ++r) acc[i][j][r] = 0.f;

    // prologue: tile 0
    gload_lds16(sA, &Alds[0][w * 512]);
    gload_lds16(sW, &Wlds[0][w * 512]);
    __syncthreads();  // drains vmcnt -> tile 0 resident

    int cur = 0;
    for (int t = 0; t < NKT; ++t) {
        if (t + 1 < NKT) {  // stage next tile into the other buffer
            const int k0 = (t + 1) * BK;
            gload_lds16(sA + k0, &Alds[cur ^ 1][w * 512]);
            gload_lds16(sW + k0, &Wlds[cur ^ 1][w * 512]);
        }
        const short8v* Ap = (const short8v*)&Alds[cur][0];
        const short8v* Wp = (const short8v*)&Wlds[cur][0];
        __builtin_amdgcn_s_setprio(1);
#pragma unroll
        for (int c = 0; c < 2; ++c) {
            short8v a[2], b[2];
#pragma unroll
            for (int m = 0; m < 2; ++m)
                a[m] = Ap[((2 * wrr + m) * 2 + c) * 64 + lane];
#pragma unroll
            for (int n = 0; n < 2; ++n)
                b[n] = Wp[((2 * wcc + n) * 2 + c) * 64 + lane];
#pragma unroll
            for (int m = 0; m < 2; ++m)
#pragma unroll
                for (int n = 0; n < 2; ++n)
                    acc[m][n] = __builtin_amdgcn_mfma_f32_32x32x16_bf16(
                        a[m], b[n], acc[m][n], 0, 0, 0);
        }
        __builtin_amdgcn_s_setprio(0);
        __syncthreads();  // my reads done; next tile's stage drained
        cur ^= 1;
    }

    // ---- epilogue: scale by winv, per-row top-2 within this 256-col block ----
    float wv[2];
#pragma unroll
    for (int n = 0; n < 2; ++n) wv[n] = winv[v0 + wcc * 64 + n * 32 + l31];

    u64(*red)[8] = (u64(*)[8]) & Alds[0][0];  // 256 rows x 8 u64 = 16 KB alias
#pragma unroll
    for (int m = 0; m < 2; ++m) {
#pragma unroll
        for (int reg = 0; reg < 16; ++reg) {
            u64 b1 = 0, b2 = 0;
#pragma unroll
            for (int n = 0; n < 2; ++n) {
                float s = acc[m][n][reg] * wv[n];
                int v = v0 + wcc * 64 + n * 32 + l31;
                u64 p = ((u64)fkey(s) << 32) | (unsigned)(Vv - 1 - v);
                top2(b1, b2, p);
            }
            // reduce over 32 cols (xor masks <32 stay within the half-wave)
#pragma unroll
            for (int msk = 1; msk < 32; msk <<= 1) {
                u64 o1 = shfl64(b1, msk);
                u64 o2 = shfl64(b2, msk);
                top2(b1, b2, o1);
                top2(b1, b2, o2);
            }
            if (l31 == 0) {
                int rl = wrr * 64 + m * 32 + (reg & 3) + 8 * (reg >> 2) + 4 * l5;
                red[rl][wcc * 2] = b1;
                red[rl][wcc * 2 + 1] = b2;
            }
        }
    }
    __syncthreads();
    if (tid < BM) {
        u64 b1 = red[tid][0], b2 = red[tid][1];
#pragma unroll
        for (int j = 2; j < 8; ++j) top2(b1, b2, red[tid][j]);
        u64* c = cand + (size_t)(row0 + tid) * CAND_STRIDE + by * 2;
        c[0] = b1;
        c[1] = b2;
    }
}

// ------ fallback epilogue (128x128 path, verified 16x16) ------
template <typename LdsT>
__device__ __forceinline__ void topk_epilogue_f(f32x4 (&acc)[4][4], LdsT* ldsbase,
                                                const float* __restrict__ winv,
                                                u64* __restrict__ cand, int row0, int v0,
                                                int vby, int tid, int lane, int wr,
                                                int wc) {
    const int cbase = v0 + wc * 64 + (lane & 15);
    float wv[4];
#pragma unroll
    for (int nf = 0; nf < 4; ++nf) wv[nf] = winv[cbase + nf * 16];

    u64(*red)[4] = (u64(*)[4])ldsbase;
#pragma unroll
    for (int mf = 0; mf < 4; ++mf) {
#pragma unroll
        for (int reg = 0; reg < 4; ++reg) {
            u64 b1 = 0, b2 = 0;
#pragma unroll
            for (int nf = 0; nf < 4; ++nf) {
                float s = acc[mf][nf][reg] * wv[nf];
                int v = cbase + nf * 16;
                u64 p = ((u64)fkey(s) << 32) | (unsigned)(Vv - 1 - v);
                top2(b1, b2, p);
            }
#pragma unroll
            for (int m = 1; m < 16; m <<= 1) {
                u64 o1 = shfl64(b1, m);
                u64 o2 = shfl64(b2, m);
                top2(b1, b2, o1);
                top2(b1, b2, o2);
            }
            if ((lane & 15) == 0) {
                int rl = wr * 64 + mf * 16 + ((lane >> 4) << 2) + reg;
                red[rl][wc * 2] = b1;
                red[rl][wc * 2 + 1] = b2;
            }
        }
    }
    __syncthreads();
    if (tid < FBM) {
        u64 b1 = red[tid][0], b2 = red[tid][1];
        top2(b1, b2, red[tid][2]);
        top2(b1, b2, red[tid][3]);
        u64* c = cand + (size_t)(row0 + tid) * CAND_STRIDE + vby * 2;
        c[0] = b1;
        c[1] = b2;
    }
}

// ---------- Kernel 3 (fallback, small ws): reg-staged f32->bf16 GEMM ----------
__global__ __launch_bounds__(256) void score_topk_fallback(
    const float* __restrict__ A, const float* __restrict__ W,
    const float* __restrict__ winv, u64* __restrict__ cand) {
    __shared__ __align__(16) short Albuf[4096];
    __shared__ __align__(16) short Wlbuf[4096];

    const int tid = threadIdx.x;
    const int row0 = blockIdx.x * FBM;
    const int v0 = blockIdx.y * FBN;
    const int lane = tid & 63;
    const int wid = tid >> 6;
    const int wr = wid >> 1, wc = wid & 1;

    const int rA = ((tid >> 6) << 4) + (tid & 15);
    const int kk = ((tid >> 4) & 3) * 8;

    const float* pa = A + (size_t)(row0 + rA) * Dk + kk;
    const float* pw = W + (size_t)(v0 + rA) * Dk + kk;

    float4 fa0, fa1, fa2, fa3, fw0, fw1, fw2, fw3;
    auto ld4 = [](const float* p) { return *(const float4*)p; };
    auto load_regs = [&](int k0) {
        fa0 = ld4(pa + k0); fa1 = ld4(pa + k0 + 4);
        fa2 = ld4(pa + k0 + (size_t)64 * Dk); fa3 = ld4(pa + k0 + (size_t)64 * Dk + 4);
        fw0 = ld4(pw + k0); fw1 = ld4(pw + k0 + 4);
        fw2 = ld4(pw + k0 + (size_t)64 * Dk); fw3 = ld4(pw + k0 + (size_t)64 * Dk + 4);
    };
    auto pk = [](float lo, float hi) {
        return (int)((__float_as_uint(lo) >> 16) | (__float_as_uint(hi) & 0xFFFF0000u));
    };
    auto cv = [&](float4 a, float4 b) {
        int4 r; r.x = pk(a.x, a.y); r.y = pk(a.z, a.w);
        r.z = pk(b.x, b.y); r.w = pk(b.z, b.w); return r;
    };
    auto write_lds = [&]() {
        *(int4*)(Albuf + tid * 8) = cv(fa0, fa1);
        *(int4*)(Albuf + tid * 8 + 2048) = cv(fa2, fa3);
        *(int4*)(Wlbuf + tid * 8) = cv(fw0, fw1);
        *(int4*)(Wlbuf + tid * 8 + 2048) = cv(fw2, fw3);
    };

    f32x4 acc[4][4];
#pragma unroll
    for (int i = 0; i < 4; ++i)
#pragma unroll
        for (int j = 0; j < 4; ++j) acc[i][j] = (f32x4){0.f, 0.f, 0.f, 0.f};

    load_regs(0);
    for (int kt = 0; kt < Dk / 32; ++kt) {
        write_lds();
        __syncthreads();
        if (kt + 1 < Dk / 32) load_regs((kt + 1) * 32);
        short8v af[4], bf[4];
        const short8v* Ap = (const short8v*)Albuf;
        const short8v* Wp = (const short8v*)Wlbuf;
#pragma unroll
        for (int mf = 0; mf < 4; ++mf) af[mf] = Ap[(wr * 4 + mf) * 64 + lane];
#pragma unroll
        for (int nf = 0; nf < 4; ++nf) bf[nf] = Wp[(wc * 4 + nf) * 64 + lane];
#pragma unroll
        for (int mf = 0; mf < 4; ++mf)
#pragma unroll
            for (int nf = 0; nf < 4; ++nf)
                acc[mf][nf] = __builtin_amdgcn_mfma_f32_16x16x32_bf16(
                    af[mf], bf[nf], acc[mf][nf], 0, 0, 0);
        __syncthreads();
    }

    topk_epilogue_f(acc, Albuf, winv, cand, row0, v0, blockIdx.y, tid, lane, wr, wc);
}

// ---------------- Kernel 4: per-row top-8 of nents candidates ----------------
__global__ __launch_bounds__(256) void topk_kernel(const u64* __restrict__ cand,
                                                   int* __restrict__ sel, int nents) {
    int row = blockIdx.x * 4 + (threadIdx.x >> 6);
    int lane = threadIdx.x & 63;
    if (row >= Mrows) return;
    const u64* c = cand + (size_t)row * CAND_STRIDE;
    u64 v[8];
#pragma unroll
    for (int i = 0; i < 8; ++i) {
        int idx = lane + i * 64;
        v[i] = (idx < nents) ? c[idx] : 0ull;
    }
#pragma unroll
    for (int it = 0; it < KCAND; ++it) {
        u64 lm = 0;
#pragma unroll
        for (int i = 0; i < 8; ++i) lm = v[i] > lm ? v[i] : lm;
#pragma unroll
        for (int m = 32; m; m >>= 1) {
            u64 o = shfl64(lm, m);
            lm = o > lm ? o : lm;
        }
#pragma unroll
        for (int i = 0; i < 8; ++i)
            if (v[i] == lm) v[i] = 0;  // packed values unique -> removes one
        if (lane == 0) sel[row * KCAND + it] = Vv - 1 - (int)(unsigned)(lm & 0xFFFFFFFFu);
    }
}

// ---------------- Kernel 5: exact f32 rescore of top-8 ----------------
__global__ __launch_bounds__(256) void rescore_kernel(
    const float* __restrict__ A, const float* __restrict__ W,
    const float* __restrict__ winv, const int* __restrict__ sel,
    u64* __restrict__ best) {
    int gw = (int)((blockIdx.x * blockDim.x + threadIdx.x) >> 6);
    int lane = threadIdx.x & 63;
    if (gw >= Mrows * KCAND) return;
    int row = gw >> 3, c = gw & 7;
    int v = sel[row * KCAND + c];
    const float4* a = (const float4*)(A + (size_t)row * Dk);
    const float4* w = (const float4*)(W + (size_t)v * Dk);
    float s = 0.f;
#pragma unroll
    for (int i = 0; i < Dk / 4 / 64; ++i) {
        float4 x = a[lane + 64 * i], y = w[lane + 64 * i];
        s = fmaf(x.x, y.x, s); s = fmaf(x.y, y.y, s);
        s = fmaf(x.z, y.z, s); s = fmaf(x.w, y.w, s);
    }
#pragma unroll
    for (int m = 32; m; m >>= 1) s += __shfl_xor(s, m, 64);
    if (lane == 0) {
        u64 p = ((u64)fkey(s * winv[v]) << 32) | (unsigned)(Vv - 1 - v);
        atomicMax(best + row, p);
    }
}

// ---------------- Kernel 6: blend + emit quantize_index ----------------
__global__ __launch_bounds__(256) void blend_kernel(
    const float* __restrict__ emb, const int* __restrict__ ids,
    const u64* __restrict__ best, float* __restrict__ out) {
    int row = blockIdx.x;
    int b = row / Tt;
    int t = row % Tt;
    int idx;
    if (t < Ll) {
        idx = Vv - 1 - (int)(best[b * Ll + t] & 0xFFFFFFFFu);
    } else {
        idx = ids[row];
    }
    const float4* src = (const float4*)(emb + (size_t)idx * Dk);
    float4* dst = (float4*)(out + (size_t)row * Dk);
    for (int i = threadIdx.x; i < Dk / 4; i += blockDim.x) dst[i] = src[i];
    if (t < Ll && threadIdx.x == 0) {
        out[(size_t)Bb * Tt * Dk + (size_t)(b * Ll + t)] = (float)idx;
    }
}

extern "C" void kernel_launch(void* const* d_in, const int* in_sizes, int n_in,
                              void* d_out, int out_size, void* d_ws, size_t ws_size,
                              hipStream_t stream) {
    const float* encoder_outs = (const float*)d_in[0];
    const float* embed_weight = (const float*)d_in[1];
    const int* input_ids = (const int*)d_in[2];

    float* out = (float*)d_out;

    float* winv = (float*)d_ws;
    u64* best = (u64*)((char*)d_ws + 131072);
    int* sel = (int*)((char*)d_ws + 147456);
    u64* cand = (u64*)((char*)d_ws + 262144);
    ushort_t* Abf = (ushort_t*)((char*)d_ws + 8454144);
    ushort_t* Wbf = (ushort_t*)((char*)d_ws + 16842752);

    init_best_kernel<<<(Mrows + 255) / 256, 256, 0, stream>>>(best);

    if (ws_size >= WS_NEEDED) {
        convertA_kernel<<<Mrows * Dk / 8 / 256, 256, 0, stream>>>(encoder_outs, Abf);
        convertW_kernel<<<Vv * 64 / 256, 256, 0, stream>>>(embed_weight, Wbf, winv);
        score_topk_kernel<<<NWG, 1024, 0, stream>>>(Abf, Wbf, winv, cand);
        topk_kernel<<<Mrows / 4, 256, 0, stream>>>(cand, sel, 2 * NBY);  // 250
    } else {
        wnorm_kernel<<<Vv * 64 / 256, 256, 0, stream>>>(embed_weight, winv);
        dim3 grid(Mrows / FBM, Vv / FBN);
        score_topk_fallback<<<grid, 256, 0, stream>>>(encoder_outs, embed_weight, winv,
                                                      cand);
        topk_kernel<<<Mrows / 4, 256, 0, stream>>>(cand, sel, 2 * FNVB);  // 500
    }
    rescore_kernel<<<Mrows * KCAND / 4, 256, 0, stream>>>(encoder_outs, embed_weight,
                                                          winv, sel, best);
    blend_kernel<<<Bb * Tt, 256, 0, stream>>>(embed_weight, input_ids, best, out);
}

// Round 12
// 947.630 us; speedup vs baseline: 4.2173x; 1.6829x over previous
//
#include <hip/hip_runtime.h>
#include <hip/hip_fp8.h>
#include <math.h>

typedef __attribute__((ext_vector_type(8))) short short8v;  // 8 bf16
typedef __attribute__((ext_vector_type(4))) float f32x4;
typedef unsigned long long u64;
typedef unsigned short ushort_t;
typedef unsigned char u8;

constexpr int Bb = 4;
constexpr int Ll = 512;
constexpr int Dk = 2048;
constexpr int Vv = 32000;
constexpr int Tt = 1024;
constexpr int Mrows = Bb * Ll;  // 2048

// main GEMM geometry: 256x256 tile, fp8 e4m3, BK=64, 16 waves (4x4 grid,
// 64x64 out each). Same skeleton as R9; operand bytes halved.
constexpr int BM = 256;
constexpr int BN = 256;
constexpr int BK = 64;
constexpr int NKT = Dk / BK;     // 32 K-tiles
constexpr int NBX = Mrows / BM;  // 8
constexpr int NBY = Vv / BN;     // 125
constexpr int NWG = NBX * NBY;   // 1000 (divisible by 8)
constexpr int CHUNK = NWG / 8;   // 125
constexpr int TILE_BYTES = 32 * 512;  // 16 KB per operand per K-tile (pre-tiled)

constexpr int KCAND = 8;          // rescored candidates per row
constexpr int CAND_STRIDE = 500;  // u64 per row; main path uses first 250

// fallback geometry (small-ws path, 128x128 reg-staged bf16)
constexpr int FBM = 128;
constexpr int FBN = 128;
constexpr int FNVB = Vv / FBN;  // 250

// ---- workspace layout (bytes) ----
// winv : f32[32000]         @ 0          (131072 B slot)
// best : u64[2048]          @ 131072     (16384 B)
// sel  : i32[2048*8]        @ 147456     (65536 B)
// cand : u64[2048*500]      @ 262144     (8192000 B)
// At   : fp8 tiled A        @ 8454144    (4194304 B)  [bx8][t32][sub32][lane64][8]
// Wt   : fp8 tiled W        @ 16842752   (65536000 B) [by125][t32][sub32][lane64][8]
constexpr size_t WS_NEEDED = 16842752ull + 65536000ull;  // 82378752

__device__ __forceinline__ unsigned int fkey(float f) {
    unsigned int u = __float_as_uint(f);
    return (u & 0x80000000u) ? ~u : (u | 0x80000000u);
}
__device__ __forceinline__ void top2(u64& b1, u64& b2, u64 p) {
    if (p > b1) { b2 = b1; b1 = p; }
    else if (p > b2) { b2 = p; }
}
__device__ __forceinline__ u64 shfl64(u64 x, int m) {
    unsigned lo = __shfl_xor((unsigned)x, m, 64);
    unsigned hi = __shfl_xor((unsigned)(x >> 32), m, 64);
    return ((u64)hi << 32) | lo;
}
__device__ __forceinline__ u8 to_e4m3(float x) {
    __hip_fp8_e4m3 q(x);  // OCP e4m3fn, RNE+sat
    return q.__x;
}
// async global->LDS, 16B per lane; global src per-lane, lds dst wave-uniform
__device__ __forceinline__ void gload_lds16(const void* g, void* l) {
    __builtin_amdgcn_global_load_lds(
        (const __attribute__((address_space(1))) unsigned int*)g,
        (__attribute__((address_space(3))) unsigned int*)l, 16, 0, 0);
}

// ---- convert A: f32 -> fp8 e4m3, pre-tiled in MFMA fragment order ----
// element (row,k): bx=row>>8, rg=(row&255)>>4, t=k>>6, c=(k>>5)&1,
// lane' = (row&15) + ((k>>3)&3)*16, byte j=k&7.
// dst byte offset = ((bx*NKT+t)*32 + rg*2+c)*512 + lane'*8 + j.
// GEMM reads back: subtile s=(rowgrp*2+c), lane l owns 8 fp8 at l*8 ->
// (row = rowgrp*16+(l&15), k = c*32+((l>>4)&3)*8+j).  [R5-verified mapping style]
__global__ __launch_bounds__(256) void convertA_fp8(const float* __restrict__ A,
                                                    u8* __restrict__ At) {
    const int row = blockIdx.x * 4 + (threadIdx.x >> 6);
    const int lane = threadIdx.x & 63;
    const int bx = row >> 8, rg = (row & 255) >> 4, r15 = row & 15;
    const float* src = A + (size_t)row * Dk;
#pragma unroll
    for (int i = 0; i < 4; ++i) {
        const int k0 = (i * 64 + lane) * 8;
        float4 x = *(const float4*)(src + k0);
        float4 y = *(const float4*)(src + k0 + 4);
        u8 o[8] = {to_e4m3(x.x), to_e4m3(x.y), to_e4m3(x.z), to_e4m3(x.w),
                   to_e4m3(y.x), to_e4m3(y.y), to_e4m3(y.z), to_e4m3(y.w)};
        const int t = k0 >> 6, c = (k0 >> 5) & 1, lp = r15 + ((k0 >> 3) & 3) * 16;
        *(u64*)(At + ((size_t)(bx * NKT + t) * 32 + rg * 2 + c) * 512 + lp * 8) =
            *(const u64*)o;
    }
}

// ---- convert W: f32 -> fp8 e4m3 (x64 uniform scale), tiled + fused winv ----
// Uniform x64 scale puts W values in e4m3 normal range; scales all scores
// uniformly -> argmax invariant. winv computed exactly from f32.
__global__ __launch_bounds__(256) void convertW_fp8(const float* __restrict__ W,
                                                    u8* __restrict__ Wt,
                                                    float* __restrict__ winv) {
    const int row = blockIdx.x * 4 + (threadIdx.x >> 6);
    const int lane = threadIdx.x & 63;
    const int by = row >> 8, rg = (row & 255) >> 4, r15 = row & 15;
    const float* src = W + (size_t)row * Dk;
    float sq = 0.f;
#pragma unroll
    for (int i = 0; i < 4; ++i) {
        const int k0 = (i * 64 + lane) * 8;
        float4 x = *(const float4*)(src + k0);
        float4 y = *(const float4*)(src + k0 + 4);
        sq = fmaf(x.x, x.x, sq); sq = fmaf(x.y, x.y, sq);
        sq = fmaf(x.z, x.z, sq); sq = fmaf(x.w, x.w, sq);
        sq = fmaf(y.x, y.x, sq); sq = fmaf(y.y, y.y, sq);
        sq = fmaf(y.z, y.z, sq); sq = fmaf(y.w, y.w, sq);
        u8 o[8] = {to_e4m3(x.x * 64.f), to_e4m3(x.y * 64.f), to_e4m3(x.z * 64.f),
                   to_e4m3(x.w * 64.f), to_e4m3(y.x * 64.f), to_e4m3(y.y * 64.f),
                   to_e4m3(y.z * 64.f), to_e4m3(y.w * 64.f)};
        const int t = k0 >> 6, c = (k0 >> 5) & 1, lp = r15 + ((k0 >> 3) & 3) * 16;
        *(u64*)(Wt + ((size_t)(by * NKT + t) * 32 + rg * 2 + c) * 512 + lp * 8) =
            *(const u64*)o;
    }
#pragma unroll
    for (int off = 32; off; off >>= 1) sq += __shfl_down(sq, off, 64);
    if (lane == 0) winv[row] = 1.0f / sqrtf(sq);
}

// ---------------- wnorm only (fallback path) ----------------
__global__ __launch_bounds__(256) void wnorm_kernel(const float* __restrict__ W,
                                                    float* __restrict__ winv) {
    int wave = (blockIdx.x * blockDim.x + threadIdx.x) >> 6;
    int lane = threadIdx.x & 63;
    if (wave >= Vv) return;
    const float4* row = (const float4*)(W + (size_t)wave * Dk);
    float s = 0.f;
#pragma unroll
    for (int i = 0; i < Dk / 4 / 64; ++i) {
        float4 v = row[lane + 64 * i];
        s = fmaf(v.x, v.x, s); s = fmaf(v.y, v.y, s);
        s = fmaf(v.z, v.z, s); s = fmaf(v.w, v.w, s);
    }
#pragma unroll
    for (int off = 32; off; off >>= 1) s += __shfl_down(s, off, 64);
    if (lane == 0) winv[wave] = 1.0f / sqrtf(s);
}

__global__ void init_best_kernel(u64* __restrict__ best) {
    int i = blockIdx.x * blockDim.x + threadIdx.x;
    if (i < Mrows) best[i] = 0ull;
}

// ========== Kernel 3 (main): fp8 e4m3 16-wave GEMM + per-block top-2 ==========
// Pre-tiled operands: per (blk, t): 32 subtiles x 512 B = 16 KB contiguous.
// Wave w stages the 1 KB chunk at offset w*1024 of each operand (linear
// gload_lds: per-lane src = base + lane*16). Frag read: ds_read_b64 at
// s*512 + lane*8, s = rowgrp*2+c. 32 MFMA/wave/tile (4m x 4n x 2c).
// C/D layout is shape-determined (16x16): same epilogue as R9 (passed).
__global__ __launch_bounds__(1024, 4) void score_topk_kernel(
    const u8* __restrict__ At, const u8* __restrict__ Wt,
    const float* __restrict__ winv, u64* __restrict__ cand) {
    __shared__ __align__(16) u8 Alds[2][TILE_BYTES];  // 2 x 16 KB
    __shared__ __align__(16) u8 Wlds[2][TILE_BYTES];  // 2 x 16 KB

    // XCD-aware bijective swizzle: 1000 = 8 x 125
    const int orig = blockIdx.x;
    const int swz = (orig & 7) * CHUNK + (orig >> 3);
    const int bx = swz & (NBX - 1);
    const int by = swz >> 3;
    const int row0 = bx * BM;
    const int v0 = by * BN;

    const int tid = threadIdx.x;
    const int lane = tid & 63;
    const int w = tid >> 6;    // 0..15
    const int wrr = w >> 2;    // 0..3 -> rows wrr*64..+63
    const int wcc = w & 3;     // 0..3 -> cols wcc*64..+63

    const u8* sA = At + (size_t)bx * NKT * TILE_BYTES + w * 1024 + lane * 16;
    const u8* sW = Wt + (size_t)by * NKT * TILE_BYTES + w * 1024 + lane * 16;

    f32x4 acc[4][4];
#pragma unroll
    for (int i = 0; i < 4; ++i)
#pragma unroll
        for (int j = 0; j < 4; ++j) acc[i][j] = (f32x4){0.f, 0.f, 0.f, 0.f};

    // prologue: tile 0
    gload_lds16(sA, &Alds[0][w * 1024]);
    gload_lds16(sW, &Wlds[0][w * 1024]);
    __syncthreads();  // tile 0 resident

    int cur = 0;
    for (int t = 0; t < NKT; ++t) {
        if (t + 1 < NKT) {  // stage next tile into the other buffer
            const size_t off = (size_t)(t + 1) * TILE_BYTES;
            gload_lds16(sA + off, &Alds[cur ^ 1][w * 1024]);
            gload_lds16(sW + off, &Wlds[cur ^ 1][w * 1024]);
        }
        __builtin_amdgcn_s_setprio(1);
#pragma unroll
        for (int c = 0; c < 2; ++c) {
            long long a[4], b[4];
#pragma unroll
            for (int m = 0; m < 4; ++m)
                a[m] = *(const long long*)&Alds[cur][(((wrr * 4 + m) * 2 + c) * 64 + lane) * 8];
#pragma unroll
            for (int n = 0; n < 4; ++n)
                b[n] = *(const long long*)&Wlds[cur][(((wcc * 4 + n) * 2 + c) * 64 + lane) * 8];
#pragma unroll
            for (int m = 0; m < 4; ++m)
#pragma unroll
                for (int n = 0; n < 4; ++n)
                    acc[m][n] = __builtin_amdgcn_mfma_f32_16x16x32_fp8_fp8(
                        a[m], b[n], acc[m][n], 0, 0, 0);
        }
        __builtin_amdgcn_s_setprio(0);
        __syncthreads();  // my reads done; next tile's stage drained
        cur ^= 1;
    }

    // ---- epilogue: scale by winv, per-row top-2 within this 256-col block ----
    const int cb = lane & 15;
    float wv[4];
#pragma unroll
    for (int n = 0; n < 4; ++n) wv[n] = winv[v0 + wcc * 64 + n * 16 + cb];

    u64(*red)[8] = (u64(*)[8]) & Alds[0][0];  // 256 rows x 8 u64 = 16 KB alias
#pragma unroll
    for (int m = 0; m < 4; ++m) {
#pragma unroll
        for (int reg = 0; reg < 4; ++reg) {
            u64 b1 = 0, b2 = 0;
#pragma unroll
            for (int n = 0; n < 4; ++n) {
                float s = acc[m][n][reg] * wv[n];
                int v = v0 + wcc * 64 + n * 16 + cb;
                u64 p = ((u64)fkey(s) << 32) | (unsigned)(Vv - 1 - v);
                top2(b1, b2, p);
            }
#pragma unroll
            for (int msk = 1; msk < 16; msk <<= 1) {
                u64 o1 = shfl64(b1, msk);
                u64 o2 = shfl64(b2, msk);
                top2(b1, b2, o1);
                top2(b1, b2, o2);
            }
            if (cb == 0) {
                int rl = wrr * 64 + m * 16 + ((lane >> 4) << 2) + reg;
                red[rl][wcc * 2] = b1;
                red[rl][wcc * 2 + 1] = b2;
            }
        }
    }
    __syncthreads();
    if (tid < BM) {
        u64 b1 = red[tid][0], b2 = red[tid][1];
#pragma unroll
        for (int j = 2; j < 8; ++j) top2(b1, b2, red[tid][j]);
        u64* c = cand + (size_t)(row0 + tid) * CAND_STRIDE + by * 2;
        c[0] = b1;
        c[1] = b2;
    }
}

// ------ fallback epilogue (128x128 bf16 path) ------
template <typename LdsT>
__device__ __forceinline__ void topk_epilogue_f(f32x4 (&acc)[4][4], LdsT* ldsbase,
                                                const float* __restrict__ winv,
                                                u64* __restrict__ cand, int row0, int v0,
                                                int vby, int tid, int lane, int wr,
                                                int wc) {
    const int cbase = v0 + wc * 64 + (lane & 15);
    float wv[4];
#pragma unroll
    for (int nf = 0; nf < 4; ++nf) wv[nf] = winv[cbase + nf * 16];

    u64(*red)[4] = (u64(*)[4])ldsbase;
#pragma unroll
    for (int mf = 0; mf < 4; ++mf) {
#pragma unroll
        for (int reg = 0; reg < 4; ++reg) {
            u64 b1 = 0, b2 = 0;
#pragma unroll
            for (int nf = 0; nf < 4; ++nf) {
                float s = acc[mf][nf][reg] * wv[nf];
                int v = cbase + nf * 16;
                u64 p = ((u64)fkey(s) << 32) | (unsigned)(Vv - 1 - v);
                top2(b1, b2, p);
            }
#pragma unroll
            for (int m = 1; m < 16; m <<= 1) {
                u64 o1 = shfl64(b1, m);
                u64 o2 = shfl64(b2, m);
                top2(b1, b2, o1);
                top2(b1, b2, o2);
            }
            if ((lane & 15) == 0) {
                int rl = wr * 64 + mf * 16 + ((lane >> 4) << 2) + reg;
                red[rl][wc * 2] = b1;
                red[rl][wc * 2 + 1] = b2;
            }
        }
    }
    __syncthreads();
    if (tid < FBM) {
        u64 b1 = red[tid][0], b2 = red[tid][1];
        top2(b1, b2, red[tid][2]);
        top2(b1, b2, red[tid][3]);
        u64* c = cand + (size_t)(row0 + tid) * CAND_STRIDE + vby * 2;
        c[0] = b1;
        c[1] = b2;
    }
}

// ---------- Kernel 3 (fallback, small ws): reg-staged f32->bf16 GEMM ----------
__global__ __launch_bounds__(256) void score_topk_fallback(
    const float* __restrict__ A, const float* __restrict__ W,
    const float* __restrict__ winv, u64* __restrict__ cand) {
    __shared__ __align__(16) short Albuf[4096];
    __shared__ __align__(16) short Wlbuf[4096];

    const int tid = threadIdx.x;
    const int row0 = blockIdx.x * FBM;
    const int v0 = blockIdx.y * FBN;
    const int lane = tid & 63;
    const int wid = tid >> 6;
    const int wr = wid >> 1, wc = wid & 1;

    const int rA = ((tid >> 6) << 4) + (tid & 15);
    const int kk = ((tid >> 4) & 3) * 8;

    const float* pa = A + (size_t)(row0 + rA) * Dk + kk;
    const float* pw = W + (size_t)(v0 + rA) * Dk + kk;

    float4 fa0, fa1, fa2, fa3, fw0, fw1, fw2, fw3;
    auto ld4 = [](const float* p) { return *(const float4*)p; };
    auto load_regs = [&](int k0) {
        fa0 = ld4(pa + k0); fa1 = ld4(pa + k0 + 4);
        fa2 = ld4(pa + k0 + (size_t)64 * Dk); fa3 = ld4(pa + k0 + (size_t)64 * Dk + 4);
        fw0 = ld4(pw + k0); fw1 = ld4(pw + k0 + 4);
        fw2 = ld4(pw + k0 + (size_t)64 * Dk); fw3 = ld4(pw + k0 + (size_t)64 * Dk + 4);
    };
    auto pk = [](float lo, float hi) {
        return (int)((__float_as_uint(lo) >> 16) | (__float_as_uint(hi) & 0xFFFF0000u));
    };
    auto cv = [&](float4 a, float4 b) {
        int4 r; r.x = pk(a.x, a.y); r.y = pk(a.z, a.w);
        r.z = pk(b.x, b.y); r.w = pk(b.z, b.w); return r;
    };
    auto write_lds = [&]() {
        *(int4*)(Albuf + tid * 8) = cv(fa0, fa1);
        *(int4*)(Albuf + tid * 8 + 2048) = cv(fa2, fa3);
        *(int4*)(Wlbuf + tid * 8) = cv(fw0, fw1);
        *(int4*)(Wlbuf + tid * 8 + 2048) = cv(fw2, fw3);
    };

    f32x4 acc[4][4];
#pragma unroll
    for (int i = 0; i < 4; ++i)
#pragma unroll
        for (int j = 0; j < 4; ++j) acc[i][j] = (f32x4){0.f, 0.f, 0.f, 0.f};

    load_regs(0);
    for (int kt = 0; kt < Dk / 32; ++kt) {
        write_lds();
        __syncthreads();
        if (kt + 1 < Dk / 32) load_regs((kt + 1) * 32);
        short8v af[4], bf[4];
        const short8v* Ap = (const short8v*)Albuf;
        const short8v* Wp = (const short8v*)Wlbuf;
#pragma unroll
        for (int mf = 0; mf < 4; ++mf) af[mf] = Ap[(wr * 4 + mf) * 64 + lane];
#pragma unroll
        for (int nf = 0; nf < 4; ++nf) bf[nf] = Wp[(wc * 4 + nf) * 64 + lane];
#pragma unroll
        for (int mf = 0; mf < 4; ++mf)
#pragma unroll
            for (int nf = 0; nf < 4; ++nf)
                acc[mf][nf] = __builtin_amdgcn_mfma_f32_16x16x32_bf16(
                    af[mf], bf[nf], acc[mf][nf], 0, 0, 0);
        __syncthreads();
    }

    topk_epilogue_f(acc, Albuf, winv, cand, row0, v0, blockIdx.y, tid, lane, wr, wc);
}

// ---------------- Kernel 4: per-row top-8 of nents candidates ----------------
__global__ __launch_bounds__(256) void topk_kernel(const u64* __restrict__ cand,
                                                   int* __restrict__ sel, int nents) {
    int row = blockIdx.x * 4 + (threadIdx.x >> 6);
    int lane = threadIdx.x & 63;
    if (row >= Mrows) return;
    const u64* c = cand + (size_t)row * CAND_STRIDE;
    u64 v[8];
#pragma unroll
    for (int i = 0; i < 8; ++i) {
        int idx = lane + i * 64;
        v[i] = (idx < nents) ? c[idx] : 0ull;
    }
#pragma unroll
    for (int it = 0; it < KCAND; ++it) {
        u64 lm = 0;
#pragma unroll
        for (int i = 0; i < 8; ++i) lm = v[i] > lm ? v[i] : lm;
#pragma unroll
        for (int m = 32; m; m >>= 1) {
            u64 o = shfl64(lm, m);
            lm = o > lm ? o : lm;
        }
#pragma unroll
        for (int i = 0; i < 8; ++i)
            if (v[i] == lm) v[i] = 0;  // packed values unique -> removes one
        if (lane == 0) sel[row * KCAND + it] = Vv - 1 - (int)(unsigned)(lm & 0xFFFFFFFFu);
    }
}

// ---------------- Kernel 5: exact f32 rescore of top-8 ----------------
__global__ __launch_bounds__(256) void rescore_kernel(
    const float* __restrict__ A, const float* __restrict__ W,
    const float* __restrict__ winv, const int* __restrict__ sel,
    u64* __restrict__ best) {
    int gw = (int)((blockIdx.x * blockDim.x + threadIdx.x) >> 6);
    int lane = threadIdx.x & 63;
    if (gw >= Mrows * KCAND) return;
    int row = gw >> 3, c = gw & 7;
    int v = sel[row * KCAND + c];
    const float4* a = (const float4*)(A + (size_t)row * Dk);
    const float4* w = (const float4*)(W + (size_t)v * Dk);
    float s = 0.f;
#pragma unroll
    for (int i = 0; i < Dk / 4 / 64; ++i) {
        float4 x = a[lane + 64 * i], y = w[lane + 64 * i];
        s = fmaf(x.x, y.x, s); s = fmaf(x.y, y.y, s);
        s = fmaf(x.z, y.z, s); s = fmaf(x.w, y.w, s);
    }
#pragma unroll
    for (int m = 32; m; m >>= 1) s += __shfl_xor(s, m, 64);
    if (lane == 0) {
        u64 p = ((u64)fkey(s * winv[v]) << 32) | (unsigned)(Vv - 1 - v);
        atomicMax(best + row, p);
    }
}

// ---------------- Kernel 6: blend + emit quantize_index ----------------
__global__ __launch_bounds__(256) void blend_kernel(
    const float* __restrict__ emb, const int* __restrict__ ids,
    const u64* __restrict__ best, float* __restrict__ out) {
    int row = blockIdx.x;
    int b = row / Tt;
    int t = row % Tt;
    int idx;
    if (t < Ll) {
        idx = Vv - 1 - (int)(best[b * Ll + t] & 0xFFFFFFFFu);
    } else {
        idx = ids[row];
    }
    const float4* src = (const float4*)(emb + (size_t)idx * Dk);
    float4* dst = (float4*)(out + (size_t)row * Dk);
    for (int i = threadIdx.x; i < Dk / 4; i += blockDim.x) dst[i] = src[i];
    if (t < Ll && threadIdx.x == 0) {
        out[(size_t)Bb * Tt * Dk + (size_t)(b * Ll + t)] = (float)idx;
    }
}

extern "C" void kernel_launch(void* const* d_in, const int* in_sizes, int n_in,
                              void* d_out, int out_size, void* d_ws, size_t ws_size,
                              hipStream_t stream) {
    const float* encoder_outs = (const float*)d_in[0];
    const float* embed_weight = (const float*)d_in[1];
    const int* input_ids = (const int*)d_in[2];

    float* out = (float*)d_out;

    float* winv = (float*)d_ws;
    u64* best = (u64*)((char*)d_ws + 131072);
    int* sel = (int*)((char*)d_ws + 147456);
    u64* cand = (u64*)((char*)d_ws + 262144);
    u8* At = (u8*)((char*)d_ws + 8454144);
    u8* Wt = (u8*)((char*)d_ws + 16842752);

    init_best_kernel<<<(Mrows + 255) / 256, 256, 0, stream>>>(best);

    if (ws_size >= WS_NEEDED) {
        convertA_fp8<<<Mrows / 4, 256, 0, stream>>>(encoder_outs, At);
        convertW_fp8<<<Vv / 4, 256, 0, stream>>>(embed_weight, Wt, winv);
        score_topk_kernel<<<NWG, 1024, 0, stream>>>(At, Wt, winv, cand);
        topk_kernel<<<Mrows / 4, 256, 0, stream>>>(cand, sel, 2 * NBY);  // 250
    } else {
        wnorm_kernel<<<Vv * 64 / 256, 256, 0, stream>>>(embed_weight, winv);
        dim3 grid(Mrows / FBM, Vv / FBN);
        score_topk_fallback<<<grid, 256, 0, stream>>>(encoder_outs, embed_weight, winv,
                                                      cand);
        topk_kernel<<<Mrows / 4, 256, 0, stream>>>(cand, sel, 2 * FNVB);  // 500
    }
    rescore_kernel<<<Mrows * KCAND / 4, 256, 0, stream>>>(encoder_outs, embed_weight,
                                                          winv, sel, best);
    blend_kernel<<<Bb * Tt, 256, 0, stream>>>(embed_weight, input_ids, best, out);
}